// Round 1
// baseline (240.543 us; speedup 1.0000x reference)
//
#include <hip/hip_runtime.h>
#include <hip/hip_bf16.h>
#include <stdint.h>

// Problem constants (from reference setup_inputs)
#define BB 64
#define SS 2048
#define DD 6
#define HH 8
#define NCH 512           // chains = B*H
#define CHUNKS 256        // chunks per chain
#define LCH 8             // steps per chunk = SS/CHUNKS

typedef unsigned short ushort_t;
typedef __attribute__((ext_vector_type(8))) __bf16 bf16x8;
typedef __attribute__((ext_vector_type(4))) float f32x4;

// ---------------- compile-time Cayley sign table (Cl(4,1)) ----------------
struct SignTab { float s[32][32]; };

constexpr int popc5_c(unsigned v) {
    int c = 0;
    for (int i = 0; i < 5; ++i) c += (v >> i) & 1u;
    return c;
}

constexpr SignTab make_signs() {
    SignTab t{};
    for (int a = 0; a < 32; ++a) {
        for (int b = 0; b < 32; ++b) {
            int cnt = 0;
            unsigned aa = ((unsigned)a) >> 1;
            while (aa) { cnt += popc5_c(aa & (unsigned)b); aa >>= 1; }
            if ((a & b) & 16) cnt += 1;   // metric: e5^2 = -1 (bit 4)
            t.s[a][b] = (cnt & 1) ? -1.0f : 1.0f;
        }
    }
    return t;
}

constexpr SignTab SGN = make_signs();

// out = a * b  (geometric product, a is LEFT operand: out_k = sum_i s(i,i^k) a_i b_{i^k})
__device__ __forceinline__ void gp_cl41(const float* __restrict__ a,
                                        const float* __restrict__ b,
                                        float* __restrict__ o) {
#pragma unroll
    for (int k = 0; k < 32; ++k) o[k] = 0.0f;
#pragma unroll
    for (int i = 0; i < 32; ++i) {
#pragma unroll
        for (int k = 0; k < 32; ++k) {
            o[k] = fmaf(SGN.s[i][i ^ k] * a[i], b[i ^ k], o[k]);
        }
    }
}

__device__ __forceinline__ float sumsq32(const float* v) {
    float n0 = 0.f, n1 = 0.f, n2 = 0.f, n3 = 0.f;
#pragma unroll
    for (int k = 0; k < 32; k += 4) {
        n0 = fmaf(v[k+0], v[k+0], n0);
        n1 = fmaf(v[k+1], v[k+1], n1);
        n2 = fmaf(v[k+2], v[k+2], n2);
        n3 = fmaf(v[k+3], v[k+3], n3);
    }
    return (n0 + n1) + (n2 + n3);
}

__device__ __forceinline__ float rsq(float n) {
    return __builtin_amdgcn_rsqf(n);   // v_rsq_f32, scale-equivalent
}

__device__ __forceinline__ uint32_t f2bf_rne(float f) {
    uint32_t u = __float_as_uint(f);
    return (u + 0x7FFFu + ((u >> 16) & 1u)) >> 16;
}

// delta = b_in(h) + W_in(h)^T x  (+1 on scalar blade); sW layout:
// sW[d*8+j4] = W_in[d][h*32+4*j4 .. +4); sW[48..55] = bias
__device__ __forceinline__ void make_delta(const float4* __restrict__ sW,
                                           const float* __restrict__ x6,
                                           float* __restrict__ dl) {
#pragma unroll
    for (int j4 = 0; j4 < 8; ++j4) {
        float4 bv = sW[48 + j4];
        dl[4*j4+0] = bv.x; dl[4*j4+1] = bv.y; dl[4*j4+2] = bv.z; dl[4*j4+3] = bv.w;
    }
#pragma unroll
    for (int d = 0; d < 6; ++d) {
        float a = x6[d];
#pragma unroll
        for (int j4 = 0; j4 < 8; ++j4) {
            float4 w = sW[d * 8 + j4];
            dl[4*j4+0] = fmaf(a, w.x, dl[4*j4+0]);
            dl[4*j4+1] = fmaf(a, w.y, dl[4*j4+1]);
            dl[4*j4+2] = fmaf(a, w.z, dl[4*j4+2]);
            dl[4*j4+3] = fmaf(a, w.w, dl[4*j4+3]);
        }
    }
    dl[0] += 1.0f;
}

// ---------------- K_A: fused chunk totals + Kogge-Stone scan -> carries ----------------
// block = one chain (b,h), thread = one chunk. Chain of 8 GPs from identity
// computed in-register (first GP folded: psi after step0 == delta0), then the
// proven Kogge-Stone scan over LDS, then exclusive carries to Ebuf (fp32).
__global__ __launch_bounds__(256, 2) void k_scan(
        const float* __restrict__ x, const float* __restrict__ W_in,
        const float* __restrict__ b_in, float* __restrict__ Ebuf) {
    __shared__ float4 sW4[57];          // this chain's h-slice of W_in + bias
    __shared__ float sT[CHUNKS][36];    // 36-float rows: 16B-aligned + bank-spread

    int chain = blockIdx.x;             // 0..511
    int b = chain >> 3, h = chain & 7;
    int c = threadIdx.x;                // chunk 0..255

    if (c < 56) {
        float4 v;
        if (c < 48) {
            int d = c / 8, j4 = c % 8;
            const float* p = W_in + d * 256 + h * 32 + 4 * j4;
            v = make_float4(p[0], p[1], p[2], p[3]);
        } else {
            const float* p = b_in + h * 32 + 4 * (c - 48);
            v = make_float4(p[0], p[1], p[2], p[3]);
        }
        sW4[c] = v;
    }
    __syncthreads();

    const float* xrow = x + ((size_t)b * SS + (size_t)c * LCH) * DD;  // 48 floats, 16B aligned

    float P[32], O[32], dl[32];

    // pair 0: psi = delta0 (free), then one GP
    {
        float xv[12];
        const float4* xp = (const float4*)xrow;
#pragma unroll
        for (int m = 0; m < 3; ++m) {
            float4 t4 = xp[m];
            xv[4*m] = t4.x; xv[4*m+1] = t4.y; xv[4*m+2] = t4.z; xv[4*m+3] = t4.w;
        }
        make_delta(sW4, xv, O);          // state after t=0
        make_delta(sW4, xv + 6, dl);
        gp_cl41(dl, O, P);               // state after t=1 (delta LEFT)
    }
#pragma unroll 1
    for (int pr = 1; pr < 4; ++pr) {
        float xv[12];
        const float4* xp = (const float4*)(xrow + 12 * pr);
#pragma unroll
        for (int m = 0; m < 3; ++m) {
            float4 t4 = xp[m];
            xv[4*m] = t4.x; xv[4*m+1] = t4.y; xv[4*m+2] = t4.z; xv[4*m+3] = t4.w;
        }
        make_delta(sW4, xv, dl);
        gp_cl41(dl, P, O);
        make_delta(sW4, xv + 6, dl);
        gp_cl41(dl, O, P);
    }

    // normalized chunk total -> v, sT
    float v[32];
    {
        float inv = rsq(sumsq32(P));
#pragma unroll
        for (int k = 0; k < 32; ++k) v[k] = P[k] * inv;
#pragma unroll
        for (int m = 0; m < 8; ++m)
            *(float4*)&sT[c][4*m] = make_float4(v[4*m], v[4*m+1], v[4*m+2], v[4*m+3]);
    }
    __syncthreads();

#pragma unroll 1
    for (int off = 1; off < CHUNKS; off <<= 1) {
        bool act = (c >= off);
        if (act) {
#pragma unroll
            for (int m = 0; m < 8; ++m) {
                float4 t4 = *(const float4*)&sT[c - off][4*m];
                O[4*m] = t4.x; O[4*m+1] = t4.y; O[4*m+2] = t4.z; O[4*m+3] = t4.w;
            }
        }
        __syncthreads();
        if (act) {
            gp_cl41(v, O, P);            // v covers newer range -> left
            float inv = rsq(sumsq32(P));
#pragma unroll
            for (int k = 0; k < 32; ++k) v[k] = P[k] * inv;
#pragma unroll
            for (int m = 0; m < 8; ++m)
                *(float4*)&sT[c][4*m] = make_float4(v[4*m], v[4*m+1], v[4*m+2], v[4*m+3]);
        }
        __syncthreads();
    }

    // exclusive carries: E_0 = identity, E_{c+1} = inclusive_c
    float* dst = Ebuf + (size_t)chain * CHUNKS * 32;
    if (c == 0) {
        *(float4*)dst = make_float4(1.f, 0.f, 0.f, 0.f);
#pragma unroll
        for (int m = 1; m < 8; ++m) *(float4*)(dst + 4*m) = make_float4(0.f, 0.f, 0.f, 0.f);
    }
    if (c < CHUNKS - 1) {
        float* d2 = dst + (size_t)(c + 1) * 32;
#pragma unroll
        for (int m = 0; m < 8; ++m)
            *(float4*)(d2 + 4*m) = make_float4(v[4*m], v[4*m+1], v[4*m+2], v[4*m+3]);
    }
}

// ---------------- K_B: chain-from-carry + MFMA projection + norm ----------------
// One wave per block; wave = (b, group of 8 chunks). lane = (cl = chunk-in-group,
// h). p starts at the scanned carry, 8 sequential steps produce the FINAL psi
// directly (no fixup GP, no psi_loc HBM roundtrip). Every 2 steps the wave has a
// complete 16x256 bf16 tile in LDS -> 16 MFMAs -> normalized rows to out.
__global__ __launch_bounds__(64, 2) void k_chain_proj(
        const float* __restrict__ x, const float* __restrict__ W_in,
        const float* __restrict__ b_in, const float* __restrict__ Ebuf,
        const float* __restrict__ W_out, const float* __restrict__ b_out,
        float* __restrict__ out) {
    __shared__ float4 sW4[8][57];       // all heads' W_in slices + bias
    __shared__ float sX[384];           // 64 s-rows x 6 floats for this (b,grp)
    __shared__ ushort_t psiT[16][264];  // 16 rows x 256 bf16 (+8 pad)

    int task = blockIdx.x;              // 0..2047
    int b = task >> 5, grp = task & 31;
    int c0 = grp * 8;                   // first chunk of group
    int lane = threadIdx.x;             // 0..63
    int cl = lane >> 3, h = lane & 7;   // chain-phase roles
    int q = lane >> 4, n0 = lane & 15;  // MFMA-phase roles

    // stage W_in/b_in (448 float4, 7 coalesced rounds)
    for (int idx = lane; idx < 448; idx += 64) {
        int hh = idx / 56, r = idx % 56;
        float4 v;
        if (r < 48) {
            int d = r / 8, j4 = r % 8;
            const float* p = W_in + d * 256 + hh * 32 + 4 * j4;
            v = make_float4(p[0], p[1], p[2], p[3]);
        } else {
            const float* p = b_in + hh * 32 + 4 * (r - 48);
            v = make_float4(p[0], p[1], p[2], p[3]);
        }
        sW4[hh][r] = v;
    }

    // stage x: 384 contiguous floats, 3 coalesced float2 per lane
    {
        const float2* xp = (const float2*)(x + ((size_t)b * SS + (size_t)c0 * LCH) * DD);
        float2* sx2 = (float2*)sX;
#pragma unroll
        for (int m = 0; m < 3; ++m) sx2[lane * 3 + m] = xp[lane * 3 + m];
    }

    // carry -> p (vectorized, prefetched before compute)
    float p[32];
    {
        const float4* ep = (const float4*)(Ebuf +
                (((size_t)b * HH + h) * CHUNKS + (c0 + cl)) * 32);
#pragma unroll
        for (int m = 0; m < 8; ++m) {
            float4 t4 = ep[m];
            p[4*m] = t4.x; p[4*m+1] = t4.y; p[4*m+2] = t4.z; p[4*m+3] = t4.w;
        }
    }

    // B-fragments in registers: B[k][n], k = kk*32 + q*8 + j, n = nt*16 + n0
    bf16x8 Bf[2][8];
#pragma unroll
    for (int nt = 0; nt < 2; ++nt)
#pragma unroll
        for (int kk = 0; kk < 8; ++kk) {
            union { ushort_t u[8]; bf16x8 v; } tmp;
#pragma unroll
            for (int j = 0; j < 8; ++j)
                tmp.u[j] = (ushort_t)f2bf_rne(W_out[(kk * 32 + q * 8 + j) * 32 + nt * 16 + n0]);
            Bf[nt][kk] = tmp.v;
        }
    float bn0 = b_out[n0], bn1 = b_out[16 + n0];

    __syncthreads();                    // sW4/sX visible (single-wave block: cheap)

#pragma unroll 1
    for (int pr = 0; pr < 4; ++pr) {    // 2 steps per round
        float x0[6], x1[6];
#pragma unroll
        for (int d = 0; d < 6; ++d) {
            x0[d] = sX[(cl * 8 + 2 * pr) * 6 + d];
            x1[d] = sX[(cl * 8 + 2 * pr + 1) * 6 + d];
        }

        float dl[32], o[32];
        make_delta(sW4[h], x0, dl);
        gp_cl41(dl, p, o);              // step 2*pr (delta LEFT); chain unnormalized
        {
            float inv = rsq(sumsq32(o));
            uint32_t pk[16];
#pragma unroll
            for (int m = 0; m < 16; ++m)
                pk[m] = f2bf_rne(o[2*m] * inv) | (f2bf_rne(o[2*m+1] * inv) << 16);
            uint4* dst = (uint4*)&psiT[cl * 2][h * 32];
#pragma unroll
            for (int m = 0; m < 4; ++m)
                dst[m] = make_uint4(pk[4*m], pk[4*m+1], pk[4*m+2], pk[4*m+3]);
        }
        make_delta(sW4[h], x1, dl);
        gp_cl41(dl, o, p);              // step 2*pr+1
        {
            float inv = rsq(sumsq32(p));
            uint32_t pk[16];
#pragma unroll
            for (int m = 0; m < 16; ++m)
                pk[m] = f2bf_rne(p[2*m] * inv) | (f2bf_rne(p[2*m+1] * inv) << 16);
            uint4* dst = (uint4*)&psiT[cl * 2 + 1][h * 32];
#pragma unroll
            for (int m = 0; m < 4; ++m)
                dst[m] = make_uint4(pk[4*m], pk[4*m+1], pk[4*m+2], pk[4*m+3]);
        }

        __syncthreads();                // cross-lane psiT visibility (wave-local)

        // projection: 16x256 @ 256x32 via 16 MFMAs
        f32x4 acc0 = {0.f, 0.f, 0.f, 0.f};
        f32x4 acc1 = {0.f, 0.f, 0.f, 0.f};
#pragma unroll
        for (int kk = 0; kk < 8; ++kk) {
            bf16x8 af = *(const bf16x8*)&psiT[n0][kk * 32 + q * 8];
            acc0 = __builtin_amdgcn_mfma_f32_16x16x32_bf16(af, Bf[0][kk], acc0, 0, 0, 0);
            acc1 = __builtin_amdgcn_mfma_f32_16x16x32_bf16(af, Bf[1][kk], acc1, 0, 0, 0);
        }

        // epilogue: bias, row-norm across 32 cols (16 lanes x 2), store
        float c0v[4], c1v[4], ssq[4];
#pragma unroll
        for (int i = 0; i < 4; ++i) {
            c0v[i] = acc0[i] + bn0;
            c1v[i] = acc1[i] + bn1;
            ssq[i] = c0v[i] * c0v[i] + c1v[i] * c1v[i];
        }
#pragma unroll
        for (int m = 1; m < 16; m <<= 1) {
#pragma unroll
            for (int i = 0; i < 4; ++i) ssq[i] += __shfl_xor(ssq[i], m);
        }
#pragma unroll
        for (int i = 0; i < 4; ++i) {
            float inv = rsq(ssq[i]);
            int mrow = q * 4 + i;       // LDS/A row = cl*2 + tt
            int s = (c0 + (mrow >> 1)) * LCH + 2 * pr + (mrow & 1);
            size_t row = (size_t)b * SS + s;
            out[row * 32 + n0]      = c0v[i] * inv;
            out[row * 32 + 16 + n0] = c1v[i] * inv;
        }

        __syncthreads();                // MFMA reads done before next round's writes
    }
}

// ---------------- launcher ----------------
extern "C" void kernel_launch(void* const* d_in, const int* in_sizes, int n_in,
                              void* d_out, int out_size, void* d_ws, size_t ws_size,
                              hipStream_t stream) {
    const float* x     = (const float*)d_in[0];
    const float* W_in  = (const float*)d_in[1];
    const float* b_in  = (const float*)d_in[2];
    const float* W_out = (const float*)d_in[3];
    const float* b_out = (const float*)d_in[4];
    float* out = (float*)d_out;

    float* Ebuf = (float*)d_ws;   // 512*256*32*4 = 16.78 MB carries (fp32)

    k_scan      <<<NCH,  256, 0, stream>>>(x, W_in, b_in, Ebuf);
    k_chain_proj<<<2048,  64, 0, stream>>>(x, W_in, b_in, Ebuf, W_out, b_out, out);
}

// Round 2
// 175.163 us; speedup vs baseline: 1.3733x; 1.3733x over previous
//
#include <hip/hip_runtime.h>
#include <hip/hip_bf16.h>
#include <stdint.h>

// Problem constants (from reference setup_inputs)
#define BB 64
#define SS 2048
#define DD 6
#define HH 8
#define NCH 512           // chains = B*H
#define CHUNKS 256        // chunks per chain
#define LCH 8             // steps per chunk = SS/CHUNKS

typedef unsigned short ushort_t;
typedef __attribute__((ext_vector_type(8))) __bf16 bf16x8;
typedef __attribute__((ext_vector_type(4))) float f32x4;

// ---------------- compile-time Cayley sign table (Cl(4,1)) ----------------
struct SignTab { float s[32][32]; };

constexpr int popc5_c(unsigned v) {
    int c = 0;
    for (int i = 0; i < 5; ++i) c += (v >> i) & 1u;
    return c;
}

constexpr SignTab make_signs() {
    SignTab t{};
    for (int a = 0; a < 32; ++a) {
        for (int b = 0; b < 32; ++b) {
            int cnt = 0;
            unsigned aa = ((unsigned)a) >> 1;
            while (aa) { cnt += popc5_c(aa & (unsigned)b); aa >>= 1; }
            if ((a & b) & 16) cnt += 1;   // metric: e5^2 = -1 (bit 4)
            t.s[a][b] = (cnt & 1) ? -1.0f : 1.0f;
        }
    }
    return t;
}

constexpr SignTab SGN = make_signs();

// out = a * b  (geometric product, a is LEFT operand: out_k = sum_i s(i,i^k) a_i b_{i^k})
__device__ __forceinline__ void gp_cl41(const float* __restrict__ a,
                                        const float* __restrict__ b,
                                        float* __restrict__ o) {
#pragma unroll
    for (int k = 0; k < 32; ++k) o[k] = 0.0f;
#pragma unroll
    for (int i = 0; i < 32; ++i) {
#pragma unroll
        for (int k = 0; k < 32; ++k) {
            o[k] = fmaf(SGN.s[i][i ^ k] * a[i], b[i ^ k], o[k]);
        }
    }
}

__device__ __forceinline__ float sumsq32(const float* v) {
    float n0 = 0.f, n1 = 0.f, n2 = 0.f, n3 = 0.f;
#pragma unroll
    for (int k = 0; k < 32; k += 4) {
        n0 = fmaf(v[k+0], v[k+0], n0);
        n1 = fmaf(v[k+1], v[k+1], n1);
        n2 = fmaf(v[k+2], v[k+2], n2);
        n3 = fmaf(v[k+3], v[k+3], n3);
    }
    return (n0 + n1) + (n2 + n3);
}

__device__ __forceinline__ float rsq(float n) {
    return __builtin_amdgcn_rsqf(n);   // v_rsq_f32, scale-equivalent
}

__device__ __forceinline__ uint32_t f2bf_rne(float f) {
    uint32_t u = __float_as_uint(f);
    return (u + 0x7FFFu + ((u >> 16) & 1u)) >> 16;
}

// delta = b_in(h) + W_in(h)^T x  (+1 on scalar blade); sW layout:
// sW[d*8+j4] = W_in[d][h*32+4*j4 .. +4); sW[48..55] = bias
__device__ __forceinline__ void make_delta(const float4* __restrict__ sW,
                                           const float* __restrict__ x6,
                                           float* __restrict__ dl) {
#pragma unroll
    for (int j4 = 0; j4 < 8; ++j4) {
        float4 bv = sW[48 + j4];
        dl[4*j4+0] = bv.x; dl[4*j4+1] = bv.y; dl[4*j4+2] = bv.z; dl[4*j4+3] = bv.w;
    }
#pragma unroll
    for (int d = 0; d < 6; ++d) {
        float a = x6[d];
#pragma unroll
        for (int j4 = 0; j4 < 8; ++j4) {
            float4 w = sW[d * 8 + j4];
            dl[4*j4+0] = fmaf(a, w.x, dl[4*j4+0]);
            dl[4*j4+1] = fmaf(a, w.y, dl[4*j4+1]);
            dl[4*j4+2] = fmaf(a, w.z, dl[4*j4+2]);
            dl[4*j4+3] = fmaf(a, w.w, dl[4*j4+3]);
        }
    }
    dl[0] += 1.0f;
}

// ---------------- K_A: fused chunk totals + Kogge-Stone scan -> carries ----------------
// block = one chain (b,h), thread = one chunk. Chain of 8 GPs from identity
// computed in-register (first GP folded: psi after step0 == delta0), then the
// Kogge-Stone scan over LDS, then exclusive carries to Ebuf (fp32).
// launch_bounds(256,1): ~120 live floats — min-waves=2 capped VGPRs at 128 and
// spilled 250 MB to scratch (round-1 FETCH_SIZE=256MB, 140us). 1-wave floor
// lets the allocator keep the GP state in registers; grid 512 = 2 blocks/CU
// still resident at <=256 VGPRs.
__global__ __launch_bounds__(256, 1) void k_scan(
        const float* __restrict__ x, const float* __restrict__ W_in,
        const float* __restrict__ b_in, float* __restrict__ Ebuf) {
    __shared__ float4 sW4[57];          // this chain's h-slice of W_in + bias
    __shared__ float sT[CHUNKS][36];    // 36-float rows: 16B-aligned + bank-spread

    int chain = blockIdx.x;             // 0..511
    int b = chain >> 3, h = chain & 7;
    int c = threadIdx.x;                // chunk 0..255

    if (c < 56) {
        float4 v;
        if (c < 48) {
            int d = c / 8, j4 = c % 8;
            const float* p = W_in + d * 256 + h * 32 + 4 * j4;
            v = make_float4(p[0], p[1], p[2], p[3]);
        } else {
            const float* p = b_in + h * 32 + 4 * (c - 48);
            v = make_float4(p[0], p[1], p[2], p[3]);
        }
        sW4[c] = v;
    }
    __syncthreads();

    const float* xrow = x + ((size_t)b * SS + (size_t)c * LCH) * DD;  // 48 floats, 16B aligned

    float P[32], O[32], dl[32];

    // pair 0: psi = delta0 (free), then one GP
    {
        float xv[12];
        const float4* xp = (const float4*)xrow;
#pragma unroll
        for (int m = 0; m < 3; ++m) {
            float4 t4 = xp[m];
            xv[4*m] = t4.x; xv[4*m+1] = t4.y; xv[4*m+2] = t4.z; xv[4*m+3] = t4.w;
        }
        make_delta(sW4, xv, O);          // state after t=0
        make_delta(sW4, xv + 6, dl);
        gp_cl41(dl, O, P);               // state after t=1 (delta LEFT)
    }
#pragma unroll 1
    for (int pr = 1; pr < 4; ++pr) {
        float xv[12];
        const float4* xp = (const float4*)(xrow + 12 * pr);
#pragma unroll
        for (int m = 0; m < 3; ++m) {
            float4 t4 = xp[m];
            xv[4*m] = t4.x; xv[4*m+1] = t4.y; xv[4*m+2] = t4.z; xv[4*m+3] = t4.w;
        }
        make_delta(sW4, xv, dl);
        gp_cl41(dl, P, O);
        make_delta(sW4, xv + 6, dl);
        gp_cl41(dl, O, P);
    }

    // normalized chunk total -> v, sT
    float v[32];
    {
        float inv = rsq(sumsq32(P));
#pragma unroll
        for (int k = 0; k < 32; ++k) v[k] = P[k] * inv;
#pragma unroll
        for (int m = 0; m < 8; ++m)
            *(float4*)&sT[c][4*m] = make_float4(v[4*m], v[4*m+1], v[4*m+2], v[4*m+3]);
    }
    __syncthreads();

#pragma unroll 1
    for (int off = 1; off < CHUNKS; off <<= 1) {
        bool act = (c >= off);
        if (act) {
#pragma unroll
            for (int m = 0; m < 8; ++m) {
                float4 t4 = *(const float4*)&sT[c - off][4*m];
                O[4*m] = t4.x; O[4*m+1] = t4.y; O[4*m+2] = t4.z; O[4*m+3] = t4.w;
            }
        }
        __syncthreads();
        if (act) {
            gp_cl41(v, O, P);            // v covers newer range -> left
            float inv = rsq(sumsq32(P));
#pragma unroll
            for (int k = 0; k < 32; ++k) v[k] = P[k] * inv;
#pragma unroll
            for (int m = 0; m < 8; ++m)
                *(float4*)&sT[c][4*m] = make_float4(v[4*m], v[4*m+1], v[4*m+2], v[4*m+3]);
        }
        __syncthreads();
    }

    // exclusive carries: E_0 = identity, E_{c+1} = inclusive_c
    float* dst = Ebuf + (size_t)chain * CHUNKS * 32;
    if (c == 0) {
        *(float4*)dst = make_float4(1.f, 0.f, 0.f, 0.f);
#pragma unroll
        for (int m = 1; m < 8; ++m) *(float4*)(dst + 4*m) = make_float4(0.f, 0.f, 0.f, 0.f);
    }
    if (c < CHUNKS - 1) {
        float* d2 = dst + (size_t)(c + 1) * 32;
#pragma unroll
        for (int m = 0; m < 8; ++m)
            *(float4*)(d2 + 4*m) = make_float4(v[4*m], v[4*m+1], v[4*m+2], v[4*m+3]);
    }
}

// ---------------- K_B: chain-from-carry + MFMA projection + norm ----------------
// One wave per block; wave = (b, group of 8 chunks). lane = (cl = chunk-in-group,
// h). p starts at the scanned carry, 8 sequential steps produce the FINAL psi
// directly (no fixup GP, no psi_loc HBM roundtrip). Every 2 steps the wave has a
// complete 16x256 bf16 tile in LDS -> 16 MFMAs -> normalized rows to out.
// (64,2): 256-VGPR cap, needs ~180; guarantees 8 single-wave blocks/CU.
__global__ __launch_bounds__(64, 2) void k_chain_proj(
        const float* __restrict__ x, const float* __restrict__ W_in,
        const float* __restrict__ b_in, const float* __restrict__ Ebuf,
        const float* __restrict__ W_out, const float* __restrict__ b_out,
        float* __restrict__ out) {
    __shared__ float4 sW4[8][57];       // all heads' W_in slices + bias
    __shared__ float sX[384];           // 64 s-rows x 6 floats for this (b,grp)
    __shared__ ushort_t psiT[16][264];  // 16 rows x 256 bf16 (+8 pad)

    int task = blockIdx.x;              // 0..2047
    int b = task >> 5, grp = task & 31;
    int c0 = grp * 8;                   // first chunk of group
    int lane = threadIdx.x;             // 0..63
    int cl = lane >> 3, h = lane & 7;   // chain-phase roles
    int q = lane >> 4, n0 = lane & 15;  // MFMA-phase roles

    // stage W_in/b_in (448 float4, 7 coalesced rounds)
    for (int idx = lane; idx < 448; idx += 64) {
        int hh = idx / 56, r = idx % 56;
        float4 v;
        if (r < 48) {
            int d = r / 8, j4 = r % 8;
            const float* p = W_in + d * 256 + hh * 32 + 4 * j4;
            v = make_float4(p[0], p[1], p[2], p[3]);
        } else {
            const float* p = b_in + hh * 32 + 4 * (r - 48);
            v = make_float4(p[0], p[1], p[2], p[3]);
        }
        sW4[hh][r] = v;
    }

    // stage x: 384 contiguous floats, 3 coalesced float2 per lane
    {
        const float2* xp = (const float2*)(x + ((size_t)b * SS + (size_t)c0 * LCH) * DD);
        float2* sx2 = (float2*)sX;
#pragma unroll
        for (int m = 0; m < 3; ++m) sx2[lane * 3 + m] = xp[lane * 3 + m];
    }

    // carry -> p (vectorized, prefetched before compute)
    float p[32];
    {
        const float4* ep = (const float4*)(Ebuf +
                (((size_t)b * HH + h) * CHUNKS + (c0 + cl)) * 32);
#pragma unroll
        for (int m = 0; m < 8; ++m) {
            float4 t4 = ep[m];
            p[4*m] = t4.x; p[4*m+1] = t4.y; p[4*m+2] = t4.z; p[4*m+3] = t4.w;
        }
    }

    // B-fragments in registers: B[k][n], k = kk*32 + q*8 + j, n = nt*16 + n0
    bf16x8 Bf[2][8];
#pragma unroll
    for (int nt = 0; nt < 2; ++nt)
#pragma unroll
        for (int kk = 0; kk < 8; ++kk) {
            union { ushort_t u[8]; bf16x8 v; } tmp;
#pragma unroll
            for (int j = 0; j < 8; ++j)
                tmp.u[j] = (ushort_t)f2bf_rne(W_out[(kk * 32 + q * 8 + j) * 32 + nt * 16 + n0]);
            Bf[nt][kk] = tmp.v;
        }
    float bn0 = b_out[n0], bn1 = b_out[16 + n0];

    __syncthreads();                    // sW4/sX visible (single-wave block: cheap)

#pragma unroll 1
    for (int pr = 0; pr < 4; ++pr) {    // 2 steps per round
        float x0[6], x1[6];
#pragma unroll
        for (int d = 0; d < 6; ++d) {
            x0[d] = sX[(cl * 8 + 2 * pr) * 6 + d];
            x1[d] = sX[(cl * 8 + 2 * pr + 1) * 6 + d];
        }

        float dl[32], o[32];
        make_delta(sW4[h], x0, dl);
        gp_cl41(dl, p, o);              // step 2*pr (delta LEFT); chain unnormalized
        {
            float inv = rsq(sumsq32(o));
            uint32_t pk[16];
#pragma unroll
            for (int m = 0; m < 16; ++m)
                pk[m] = f2bf_rne(o[2*m] * inv) | (f2bf_rne(o[2*m+1] * inv) << 16);
            uint4* dst = (uint4*)&psiT[cl * 2][h * 32];
#pragma unroll
            for (int m = 0; m < 4; ++m)
                dst[m] = make_uint4(pk[4*m], pk[4*m+1], pk[4*m+2], pk[4*m+3]);
        }
        make_delta(sW4[h], x1, dl);
        gp_cl41(dl, o, p);              // step 2*pr+1
        {
            float inv = rsq(sumsq32(p));
            uint32_t pk[16];
#pragma unroll
            for (int m = 0; m < 16; ++m)
                pk[m] = f2bf_rne(p[2*m] * inv) | (f2bf_rne(p[2*m+1] * inv) << 16);
            uint4* dst = (uint4*)&psiT[cl * 2 + 1][h * 32];
#pragma unroll
            for (int m = 0; m < 4; ++m)
                dst[m] = make_uint4(pk[4*m], pk[4*m+1], pk[4*m+2], pk[4*m+3]);
        }

        __syncthreads();                // cross-lane psiT visibility (wave-local)

        // projection: 16x256 @ 256x32 via 16 MFMAs
        f32x4 acc0 = {0.f, 0.f, 0.f, 0.f};
        f32x4 acc1 = {0.f, 0.f, 0.f, 0.f};
#pragma unroll
        for (int kk = 0; kk < 8; ++kk) {
            bf16x8 af = *(const bf16x8*)&psiT[n0][kk * 32 + q * 8];
            acc0 = __builtin_amdgcn_mfma_f32_16x16x32_bf16(af, Bf[0][kk], acc0, 0, 0, 0);
            acc1 = __builtin_amdgcn_mfma_f32_16x16x32_bf16(af, Bf[1][kk], acc1, 0, 0, 0);
        }

        // epilogue: bias, row-norm across 32 cols (16 lanes x 2), store
        float c0v[4], c1v[4], ssq[4];
#pragma unroll
        for (int i = 0; i < 4; ++i) {
            c0v[i] = acc0[i] + bn0;
            c1v[i] = acc1[i] + bn1;
            ssq[i] = c0v[i] * c0v[i] + c1v[i] * c1v[i];
        }
#pragma unroll
        for (int m = 1; m < 16; m <<= 1) {
#pragma unroll
            for (int i = 0; i < 4; ++i) ssq[i] += __shfl_xor(ssq[i], m);
        }
#pragma unroll
        for (int i = 0; i < 4; ++i) {
            float inv = rsq(ssq[i]);
            int mrow = q * 4 + i;       // LDS/A row = cl*2 + tt
            int s = (c0 + (mrow >> 1)) * LCH + 2 * pr + (mrow & 1);
            size_t row = (size_t)b * SS + s;
            out[row * 32 + n0]      = c0v[i] * inv;
            out[row * 32 + 16 + n0] = c1v[i] * inv;
        }

        __syncthreads();                // MFMA reads done before next round's writes
    }
}

// ---------------- launcher ----------------
extern "C" void kernel_launch(void* const* d_in, const int* in_sizes, int n_in,
                              void* d_out, int out_size, void* d_ws, size_t ws_size,
                              hipStream_t stream) {
    const float* x     = (const float*)d_in[0];
    const float* W_in  = (const float*)d_in[1];
    const float* b_in  = (const float*)d_in[2];
    const float* W_out = (const float*)d_in[3];
    const float* b_out = (const float*)d_in[4];
    float* out = (float*)d_out;

    float* Ebuf = (float*)d_ws;   // 512*256*32*4 = 16.78 MB carries (fp32)

    k_scan      <<<NCH,  256, 0, stream>>>(x, W_in, b_in, Ebuf);
    k_chain_proj<<<2048,  64, 0, stream>>>(x, W_in, b_in, Ebuf, W_out, b_out, out);
}